// Round 1
// baseline (172.286 us; speedup 1.0000x reference)
//
#include <hip/hip_runtime.h>
#include <hip/hip_bf16.h>
#include <math.h>

// Problem: SUB_Independent_Loss — contrastive pairwise loss, single f32 scalar out.
// N1 = N2 = 256, D = 1024.
//
// ws layout:
//   [0)        sims: 3 * 256*256 f32  (sim12, sim11, sim22)   = 786432 B
//   [786432)   sel1: 256 f32
//   [787456)   sel2: 256 f32
//   [788480)   lossAcc: double
//   [788488)   pairAcc: unsigned long long

#define NN 256
#define DD 1024

// ---------------------------------------------------------------------------
// Kernel 1: decode mask_sents (bool-bytes or int32 — auto-detect), zero accums.
// Detection: int32 0/1 data has all-zero bytes at positions i%4 != 0 within the
// first 256 bytes; random bool data has ~96 nonzero ones there. Both-zero case
// (all-false mask) gives identical results under either interpretation.
// ---------------------------------------------------------------------------
__global__ void prep_kernel(const void* ms1, const void* ms2,
                            float* sel1, float* sel2,
                            double* lossAcc, unsigned long long* pairAcc) {
    int tid = threadIdx.x;
    __shared__ int nz1, nz2;
    if (tid == 0) { nz1 = 0; nz2 = 0; }
    __syncthreads();
    const unsigned char* b1 = (const unsigned char*)ms1;
    const unsigned char* b2 = (const unsigned char*)ms2;
    if ((tid & 3) != 0) {
        if (b1[tid] != 0) atomicOr(&nz1, 1);
        if (b2[tid] != 0) atomicOr(&nz2, 1);
    }
    __syncthreads();
    if (nz1 != 0) {               // raw bool bytes
        sel1[tid] = b1[tid] ? 1.0f : 0.0f;
    } else {                      // int32
        sel1[tid] = (float)((const int*)ms1)[tid];
    }
    if (nz2 != 0) {
        sel2[tid] = b2[tid] ? 1.0f : 0.0f;
    } else {
        sel2[tid] = (float)((const int*)ms2)[tid];
    }
    if (tid == 0) { *lossAcc = 0.0; *pairAcc = 0ULL; }
}

// ---------------------------------------------------------------------------
// Kernel 2: three NT GEMMs (C = X @ Y^T), fp32 vector ALU.
// blockIdx.z selects matrix: 0 -> f1@f2^T, 1 -> f1@f1^T, 2 -> f2@f2^T.
// 32x32 output tile per 256-thread block, K-chunks of 32 staged in LDS.
// ---------------------------------------------------------------------------
__global__ __launch_bounds__(256) void gemm_nt(const float* __restrict__ F1,
                                               const float* __restrict__ F2,
                                               float* __restrict__ sims) {
    const int m = blockIdx.z;
    const float* A = (m == 2) ? F2 : F1;
    const float* B = (m == 0) ? F2 : ((m == 1) ? F1 : F2);
    float* C = sims + m * (NN * NN);

    __shared__ float As[32][33];
    __shared__ float Bs[32][33];

    const int tid = threadIdx.x;
    const int tx = tid & 31;   // output col within tile
    const int ty = tid >> 5;   // 0..7, output row group
    const int row0 = blockIdx.x * 32;
    const int col0 = blockIdx.y * 32;

    float acc0 = 0.f, acc1 = 0.f, acc2 = 0.f, acc3 = 0.f;

    for (int k0 = 0; k0 < DD; k0 += 32) {
#pragma unroll
        for (int q = 0; q < 4; q++) {
            int idx = tid + q * 256;
            int r = idx >> 5, c = idx & 31;
            As[r][c] = A[(row0 + r) * DD + k0 + c];
            Bs[r][c] = B[(col0 + r) * DD + k0 + c];
        }
        __syncthreads();
#pragma unroll
        for (int kk = 0; kk < 32; kk++) {
            float b = Bs[tx][kk];
            acc0 += As[ty][kk] * b;
            acc1 += As[ty + 8][kk] * b;
            acc2 += As[ty + 16][kk] * b;
            acc3 += As[ty + 24][kk] * b;
        }
        __syncthreads();
    }
    C[(row0 + ty) * NN + col0 + tx] = acc0;
    C[(row0 + ty + 8) * NN + col0 + tx] = acc1;
    C[(row0 + ty + 16) * NN + col0 + tx] = acc2;
    C[(row0 + ty + 24) * NN + col0 + tx] = acc3;
}

// ---------------------------------------------------------------------------
// Kernel 3: loss. grid (256 rows, 4 calls), 256 threads/block.
// call 0: sim12 row i,   mc row i,    sel1[i]
// call 1: sim12 col i,   mc col i,    sel2[i]   (the transposed call)
// call 2: sim11 row i,   m1 row i,    sel1[i]
// call 3: sim22 row i,   m2 row i,    sel2[i]
// Per row: compact pos (mask=1) / neg (mask=0) column indices in LDS, then
// enumerate pos x neg pairs, accumulate softplus(s_neg - s_pos).
// ---------------------------------------------------------------------------
__global__ __launch_bounds__(256) void loss_kernel(const float* __restrict__ sims,
                                                   const int* __restrict__ mc,
                                                   const int* __restrict__ m1,
                                                   const int* __restrict__ m2,
                                                   const float* __restrict__ sel1,
                                                   const float* __restrict__ sel2,
                                                   double* lossAcc,
                                                   unsigned long long* pairAcc) {
    const int i = blockIdx.x;
    const int c = blockIdx.y;
    const int tid = threadIdx.x;

    const float* sim12 = sims;
    const float* sim11 = sims + NN * NN;
    const float* sim22 = sims + 2 * NN * NN;

    float sel;
    float simv;
    int maskv;
    if (c == 0) {
        sel = sel1[i]; simv = sim12[i * NN + tid]; maskv = mc[i * NN + tid];
    } else if (c == 1) {
        sel = sel2[i]; simv = sim12[tid * NN + i]; maskv = mc[tid * NN + i];
    } else if (c == 2) {
        sel = sel1[i]; simv = sim11[i * NN + tid]; maskv = m1[i * NN + tid];
    } else {
        sel = sel2[i]; simv = sim22[i * NN + tid]; maskv = m2[i * NN + tid];
    }
    if (sel == 0.0f) return;  // uniform across block

    __shared__ float s[NN];
    __shared__ unsigned short posIdx[NN];
    __shared__ unsigned short negIdx[NN];
    __shared__ int cnt[2];
    __shared__ double red[4];

    if (tid == 0) { cnt[0] = 0; cnt[1] = 0; }
    __syncthreads();
    s[tid] = simv;
    if (maskv != 0) {
        int p = atomicAdd(&cnt[0], 1);
        posIdx[p] = (unsigned short)tid;
    } else {
        int p = atomicAdd(&cnt[1], 1);
        negIdx[p] = (unsigned short)tid;
    }
    __syncthreads();

    const int np_ = cnt[0];
    const int nn_ = cnt[1];
    const int total = np_ * nn_;
    if (total == 0) return;  // uniform across block

    if (tid == 0) atomicAdd(pairAcc, (unsigned long long)total);

    const float inv = 1.0f / (float)nn_;
    double local = 0.0;
    for (int t = tid; t < total; t += 256) {
        int jj = (int)((float)t * inv);
        int kk = t - jj * nn_;
        if (kk < 0) { jj--; kk += nn_; }
        else if (kk >= nn_) { jj++; kk -= nn_; }
        float x = s[negIdx[kk]] - s[posIdx[jj]];           // s_neg - s_pos
        float sp = fmaxf(x, 0.0f) + log1pf(__expf(-fabsf(x)));
        local += (double)sp;
    }

    // block reduction (4 waves of 64)
    double v = local;
#pragma unroll
    for (int off = 32; off > 0; off >>= 1) v += __shfl_down(v, off, 64);
    if ((tid & 63) == 0) red[tid >> 6] = v;
    __syncthreads();
    if (tid == 0) {
        double bsum = red[0] + red[1] + red[2] + red[3];
        atomicAdd(lossAcc, bsum);
    }
}

// ---------------------------------------------------------------------------
// Kernel 4: finalize scalar.
// ---------------------------------------------------------------------------
__global__ void finalize_kernel(const double* lossAcc,
                                const unsigned long long* pairAcc,
                                float* out) {
    double loss = *lossAcc;
    unsigned long long p = *pairAcc;
    double r = (p > 0ULL) ? (loss / (double)p) : loss;
    out[0] = (float)r;
}

extern "C" void kernel_launch(void* const* d_in, const int* in_sizes, int n_in,
                              void* d_out, int out_size, void* d_ws, size_t ws_size,
                              hipStream_t stream) {
    const float* f1 = (const float*)d_in[0];
    const float* f2 = (const float*)d_in[1];
    const int* mc = (const int*)d_in[2];
    const int* m1 = (const int*)d_in[3];
    const int* m2 = (const int*)d_in[4];
    const void* ms1 = d_in[5];
    const void* ms2 = d_in[6];

    char* ws = (char*)d_ws;
    float* sims = (float*)ws;                                  // 3 * 65536 f32
    float* sel1 = (float*)(ws + 786432);
    float* sel2 = (float*)(ws + 787456);
    double* lossAcc = (double*)(ws + 788480);
    unsigned long long* pairAcc = (unsigned long long*)(ws + 788488);

    prep_kernel<<<1, 256, 0, stream>>>(ms1, ms2, sel1, sel2, lossAcc, pairAcc);
    gemm_nt<<<dim3(8, 8, 3), 256, 0, stream>>>(f1, f2, sims);
    loss_kernel<<<dim3(256, 4), 256, 0, stream>>>(sims, mc, m1, m2, sel1, sel2,
                                                  lossAcc, pairAcc);
    finalize_kernel<<<1, 1, 0, stream>>>(lossAcc, pairAcc, (float*)d_out);
}

// Round 2
// 92.182 us; speedup vs baseline: 1.8690x; 1.8690x over previous
//
#include <hip/hip_runtime.h>
#include <hip/hip_bf16.h>
#include <math.h>

// SUB_Independent_Loss — contrastive pairwise loss, single f32 scalar out.
// N1 = N2 = 256, D = 1024.
//
// ws layout:
//   [0)         sims: 3 * 256*256 f32 (sim12, sim11, sim22)  = 786432 B
//   [786432)    b1: 256*1024 bf16 (f1)                       = 524288 B
//   [1310720)   b2: 256*1024 bf16 (f2)                       = 524288 B
//   [1835008)   sel1: 256 f32
//   [1836032)   sel2: 256 f32
//   [1837056)   lossAcc: double
//   [1837064)   pairAcc: unsigned long long

#define NN 256
#define DD 1024

typedef __attribute__((ext_vector_type(8))) short short8;   // 8 bf16 = 4 VGPRs
typedef __attribute__((ext_vector_type(4))) float f32x4;

__device__ __forceinline__ unsigned short f32_to_bf16_rne(float x) {
    unsigned int u = __float_as_uint(x);
    u += 0x7fffu + ((u >> 16) & 1u);     // round to nearest even (inputs are finite)
    return (unsigned short)(u >> 16);
}

// ---------------------------------------------------------------------------
// Kernel 1: blocks 0..511 convert f1/f2 f32 -> bf16 (RNE). Block 512 decodes
// mask_sents (bool-bytes or int32 auto-detect) and zeroes the accumulators.
// Detection: int32 0/1 data has all-zero bytes at i%4!=0 in the first 256 B;
// random bool data has ~96 nonzero ones there (misdetect prob ~2^-192).
// ---------------------------------------------------------------------------
__global__ __launch_bounds__(256) void convert_prep_kernel(
        const float* __restrict__ f1, const float* __restrict__ f2,
        unsigned short* __restrict__ b1, unsigned short* __restrict__ b2,
        const void* ms1, const void* ms2,
        float* sel1, float* sel2,
        double* lossAcc, unsigned long long* pairAcc) {
    const int bid = blockIdx.x;
    const int tid = threadIdx.x;
    if (bid < 512) {
        const float* src = (bid < 256) ? f1 : f2;
        unsigned short* dst = (bid < 256) ? b1 : b2;
        int base = ((bid & 255) * 256 + tid) * 4;       // 4 floats per thread
        float4 v = *(const float4*)(src + base);
        ushort4 o;
        o.x = f32_to_bf16_rne(v.x);
        o.y = f32_to_bf16_rne(v.y);
        o.z = f32_to_bf16_rne(v.z);
        o.w = f32_to_bf16_rne(v.w);
        *(ushort4*)(dst + base) = o;
    } else {
        __shared__ int nz1, nz2;
        if (tid == 0) { nz1 = 0; nz2 = 0; }
        __syncthreads();
        const unsigned char* c1 = (const unsigned char*)ms1;
        const unsigned char* c2 = (const unsigned char*)ms2;
        if ((tid & 3) != 0) {
            if (c1[tid] != 0) atomicOr(&nz1, 1);
            if (c2[tid] != 0) atomicOr(&nz2, 1);
        }
        __syncthreads();
        sel1[tid] = (nz1 != 0) ? (c1[tid] ? 1.0f : 0.0f)
                               : (float)((const int*)ms1)[tid];
        sel2[tid] = (nz2 != 0) ? (c2[tid] ? 1.0f : 0.0f)
                               : (float)((const int*)ms2)[tid];
        if (tid == 0) { *lossAcc = 0.0; *pairAcc = 0ULL; }
    }
}

// ---------------------------------------------------------------------------
// Kernel 2: three NT GEMMs via bf16 MFMA. One wave per 16x16 output tile,
// full K=1024 (32 mfma). 768 tiles -> 192 blocks x 4 waves. Fragments loaded
// directly from global (L2-resident).
// A-operand layout: lane holds A[m=lane&15][k = (lane>>4)*8 + j], j=0..7.
// B-operand (NT): same addressing on the B matrix rows (= output cols).
// C/D layout: col = lane&15, row = (lane>>4)*4 + reg.
// ---------------------------------------------------------------------------
__global__ __launch_bounds__(256) void gemm_mfma(
        const unsigned short* __restrict__ b1,
        const unsigned short* __restrict__ b2,
        float* __restrict__ sims) {
    const int gwave = blockIdx.x * 4 + (threadIdx.x >> 6);  // 0..767
    const int m = gwave >> 8;                               // matrix 0..2
    const int t = gwave & 255;                              // tile 0..255
    const int tr = t >> 4, tc = t & 15;
    const unsigned short* A  = (m == 2) ? b2 : b1;
    const unsigned short* Bm = (m == 0) ? b2 : ((m == 1) ? b1 : b2);
    float* C = sims + m * (NN * NN);

    const int lane = threadIdx.x & 63;
    const int r = lane & 15;
    const int quad = lane >> 4;

    const unsigned short* aptr = A  + (tr * 16 + r) * DD + quad * 8;
    const unsigned short* bptr = Bm + (tc * 16 + r) * DD + quad * 8;

    f32x4 acc = {0.f, 0.f, 0.f, 0.f};
#pragma unroll 8
    for (int k0 = 0; k0 < DD; k0 += 32) {
        short8 af = *(const short8*)(aptr + k0);
        short8 bf = *(const short8*)(bptr + k0);
        acc = __builtin_amdgcn_mfma_f32_16x16x32_bf16(af, bf, acc, 0, 0, 0);
    }
    const int row0 = tr * 16 + quad * 4;
    const int col = tc * 16 + (lane & 15);
#pragma unroll
    for (int rr = 0; rr < 4; rr++) {
        C[(row0 + rr) * NN + col] = acc[rr];
    }
}

// ---------------------------------------------------------------------------
// Kernel 3: loss. grid (256 rows, 4 calls), 256 threads/block.
// call 0: sim12 row i / mc row i / sel1;  call 1: sim12 col i / mc col i / sel2
// call 2: sim11 row i / m1 row i / sel1;  call 3: sim22 row i / m2 row i / sel2
// Ballot-compact pos/neg values (pre-scaled by log2e) into LDS; each thread
// holds one neg in a register (pad -1e30 => exact 0 contribution), loops over
// pos with LDS broadcast reads. softplus(x)/ln2 = max(x2,0)+log2(1+2^-|x2|).
// ---------------------------------------------------------------------------
__global__ __launch_bounds__(256) void loss_kernel(
        const float* __restrict__ sims,
        const int* __restrict__ mc,
        const int* __restrict__ m1,
        const int* __restrict__ m2,
        const float* __restrict__ sel1,
        const float* __restrict__ sel2,
        double* lossAcc, unsigned long long* pairAcc) {
    const int i = blockIdx.x;
    const int c = blockIdx.y;
    const int tid = threadIdx.x;

    const float* sim12 = sims;
    const float* sim11 = sims + NN * NN;
    const float* sim22 = sims + 2 * NN * NN;

    float sel, simv;
    int maskv;
    if (c == 0) {
        sel = sel1[i]; simv = sim12[i * NN + tid]; maskv = mc[i * NN + tid];
    } else if (c == 1) {
        sel = sel2[i]; simv = sim12[tid * NN + i]; maskv = mc[tid * NN + i];
    } else if (c == 2) {
        sel = sel1[i]; simv = sim11[i * NN + tid]; maskv = m1[i * NN + tid];
    } else {
        sel = sel2[i]; simv = sim22[i * NN + tid]; maskv = m2[i * NN + tid];
    }
    if (sel == 0.0f) return;  // block-uniform

    const float LOG2E = 1.4426950408889634f;
    const float LN2   = 0.6931471805599453f;

    __shared__ float sPos[NN];
    __shared__ float sNeg[NN];
    __shared__ int wcnt[4];
    __shared__ float red[4];

    const int lane = tid & 63;
    const int w = tid >> 6;
    const bool pos = (maskv != 0);
    unsigned long long bal = __ballot(pos);
    if (lane == 0) wcnt[w] = __popcll(bal);
    __syncthreads();

    int posBase = 0, np_ = 0;
#pragma unroll
    for (int q = 0; q < 4; q++) {
        int v = wcnt[q];
        if (q < w) posBase += v;
        np_ += v;
    }
    const int nn_ = NN - np_;

    const unsigned long long ltmask = (1ull << lane) - 1ull;
    const int pp = __popcll(bal & ltmask);
    const float tval = simv * LOG2E;
    if (pos) sPos[posBase + pp] = tval;
    else     sNeg[(w * 64 - posBase) + (lane - pp)] = tval;
    __syncthreads();

    if (np_ == 0 || nn_ == 0) return;  // block-uniform
    if (tid == 0) atomicAdd(pairAcc, (unsigned long long)(np_ * nn_));

    const float tn = (tid < nn_) ? sNeg[tid] : -1e30f;  // pad => 0 contribution
    float accL = 0.f, accM = 0.f;
    for (int jj = 0; jj < np_; jj++) {
        float sp = sPos[jj];                  // broadcast, conflict-free
        float x2 = tn - sp;                   // (s_neg - s_pos) * log2e
        float e = __builtin_amdgcn_exp2f(-fabsf(x2));
        accL += __builtin_amdgcn_logf(1.0f + e);   // log2(1+e)
        accM += fmaxf(x2, 0.0f);
    }
    float local = (accL + accM) * LN2;

    // block reduction (4 waves of 64)
#pragma unroll
    for (int off = 32; off > 0; off >>= 1) local += __shfl_down(local, off, 64);
    if (lane == 0) red[w] = local;
    __syncthreads();
    if (tid == 0) {
        double bsum = (double)red[0] + (double)red[1] +
                      (double)red[2] + (double)red[3];
        atomicAdd(lossAcc, bsum);
    }
}

// ---------------------------------------------------------------------------
// Kernel 4: finalize scalar.
// ---------------------------------------------------------------------------
__global__ void finalize_kernel(const double* lossAcc,
                                const unsigned long long* pairAcc,
                                float* out) {
    double loss = *lossAcc;
    unsigned long long p = *pairAcc;
    double r = (p > 0ULL) ? (loss / (double)p) : loss;
    out[0] = (float)r;
}

extern "C" void kernel_launch(void* const* d_in, const int* in_sizes, int n_in,
                              void* d_out, int out_size, void* d_ws, size_t ws_size,
                              hipStream_t stream) {
    const float* f1 = (const float*)d_in[0];
    const float* f2 = (const float*)d_in[1];
    const int* mc = (const int*)d_in[2];
    const int* m1 = (const int*)d_in[3];
    const int* m2 = (const int*)d_in[4];
    const void* ms1 = d_in[5];
    const void* ms2 = d_in[6];

    char* ws = (char*)d_ws;
    float* sims          = (float*)ws;                       // 786432 B
    unsigned short* b1   = (unsigned short*)(ws + 786432);   // 524288 B
    unsigned short* b2   = (unsigned short*)(ws + 1310720);  // 524288 B
    float* sel1          = (float*)(ws + 1835008);
    float* sel2          = (float*)(ws + 1836032);
    double* lossAcc      = (double*)(ws + 1837056);
    unsigned long long* pairAcc = (unsigned long long*)(ws + 1837064);

    convert_prep_kernel<<<513, 256, 0, stream>>>(f1, f2, b1, b2, ms1, ms2,
                                                 sel1, sel2, lossAcc, pairAcc);
    gemm_mfma<<<192, 256, 0, stream>>>(b1, b2, sims);
    loss_kernel<<<dim3(256, 4), 256, 0, stream>>>(sims, mc, m1, m2, sel1, sel2,
                                                  lossAcc, pairAcc);
    finalize_kernel<<<1, 1, 0, stream>>>(lossAcc, pairAcc, (float*)d_out);
}